// Round 2
// baseline (1023.130 us; speedup 1.0000x reference)
//
#include <hip/hip_runtime.h>
#include <cstddef>
#include <cstdint>

// R4: structural rev.
//  - gemm_bf16: T3-minimum 2-phase pipeline (double-buffered LDS, stage(t+1)
//    issued BEFORE compute(t), ONE barrier per K-step) — attacks the
//    vmcnt(0)-drain stall that the R3 swizzle experiment showed was not LDS.
//  - convert_adj fused into GEMM1 (reads adj f32 once, emits bf16 adjb as a
//    side product while computing g1 partials): -202 MB HBM.
//  - recon GEMM: dedicated 128x128-tile kernel (32 MFMA/wave/K-step, half the
//    staging per output byte, 6241 blocks instead of 12403).
//  - reduce+tanh+transpose fused for z2 (z2 f32 intermediate eliminated).
//
// Math (exact-equivalent restructure of reference):
//   g1   = adj @ z_igae          [N,20]
//   z1   = tanh(g1 @ w3)         [N,256]
//   t2   = z1 @ w4               [N,128]
//   z2   = tanh(adj @ t2)        [N,128]
//   g3   = adj @ z2              [N,128]
//   zhat = g3 @ w5               [N,500]             -> out0
//   Mm   = w5 @ w5^T             [128,128]
//   h    = g3 @ Mm               [N,128]
//   out1 = sigmoid(h @ g3^T)     [N,N]               -> out1

typedef __attribute__((ext_vector_type(8))) short bf16x8;
typedef __attribute__((ext_vector_type(4))) float f32x4;

#define NROWS 10000
#define MP 10048    // padded to multiple of 64
#define MP2 10112   // 79*128, recon-tile padding

__device__ inline unsigned short f2bf(float f) {
  union { float f; unsigned int u; } a; a.f = f;
  unsigned int u = a.u;
  u += 0x7fffu + ((u >> 16) & 1u);  // round-to-nearest-even
  return (unsigned short)(u >> 16);
}

__device__ inline void gl_lds16(const void* g, void* l) {
  __builtin_amdgcn_global_load_lds(
      (const __attribute__((address_space(1))) void*)g,
      (__attribute__((address_space(3))) void*)l, 16, 0, 0);
}

// ---------------------------------------------------------------------------
// GEMM1 fused with adj f32->bf16 conversion.
// Computes P[s] = (adj @ z_igae^T-operand) partials AND writes adjb (bf16,
// zero-padded [MP][MP]) as a side product. Each adj element is read exactly
// once across the (y,s) grid. Tile 64x32, BK=64.
// ---------------------------------------------------------------------------
__global__ __launch_bounds__(256)
void gemm1_fused(const float* __restrict__ adj, const short* __restrict__ zt,
                 short* __restrict__ adjb, float* __restrict__ P,
                 int kChunks, int S) {
  __shared__ short As[64 * 64];
  __shared__ short Bs[32 * 64];
  const int tid  = threadIdx.x;
  const int wave = tid >> 6;
  const int lane = tid & 63;
  const int row0 = blockIdx.y * 64;
  const int s    = blockIdx.z;
  const int t0 = (int)((long long)s * kChunks / S);
  const int t1 = (int)((long long)(s + 1) * kChunks / S);

  f32x4 acc[2];
#pragma unroll
  for (int i = 0; i < 2; ++i) acc[i] = (f32x4){0.f, 0.f, 0.f, 0.f};

  const int lr = lane >> 3;
  const int lk = ((lane & 7) ^ lr) * 8;   // swizzled source granule for B
  const int fr = lane & 15, fq = lane >> 4, sw = lane & 7;

  const int ar  = tid >> 2;      // A-stage row 0..63
  const int acq = tid & 3;       // col quarter (16 f32)
  const int gr  = row0 + ar;
  const bool rv = gr < NROWS;

  for (int t = t0; t < t1; ++t) {
    const int k0 = t * 64;
    __syncthreads();
    // B: 4 chunks of 1 KB, one per wave, src-swizzled
    gl_lds16(zt + (size_t)(8 * wave + lr) * MP + k0 + lk, (void*)(Bs + wave * 512));
    // A: 16 f32 per thread, convert, LDS-write (swizzled) + adjb side-write
    const int gc = k0 + acq * 16;
    float4 f[4];
#pragma unroll
    for (int j = 0; j < 4; ++j) {
      int c = gc + 4 * j;
      f[j] = (rv && c < NROWS) ? *(const float4*)(adj + (size_t)gr * NROWS + c)
                               : make_float4(0.f, 0.f, 0.f, 0.f);
    }
    unsigned short h[16] __attribute__((aligned(16)));
#pragma unroll
    for (int j = 0; j < 4; ++j) {
      h[4 * j + 0] = f2bf(f[j].x); h[4 * j + 1] = f2bf(f[j].y);
      h[4 * j + 2] = f2bf(f[j].z); h[4 * j + 3] = f2bf(f[j].w);
    }
    *(uint4*)(adjb + (size_t)gr * MP + gc)     = *(const uint4*)&h[0];
    *(uint4*)(adjb + (size_t)gr * MP + gc + 8) = *(const uint4*)&h[8];
    *(bf16x8*)&As[ar * 64 + ((acq * 2 + 0) ^ (ar & 7)) * 8] = *(const bf16x8*)&h[0];
    *(bf16x8*)&As[ar * 64 + ((acq * 2 + 1) ^ (ar & 7)) * 8] = *(const bf16x8*)&h[8];
    __syncthreads();
#pragma unroll
    for (int ks = 0; ks < 2; ++ks) {
      const int go = ((ks * 4 + fq) ^ sw) * 8;
      bf16x8 af = *(const bf16x8*)&As[(wave * 16 + fr) * 64 + go];
#pragma unroll
      for (int nt = 0; nt < 2; ++nt) {
        bf16x8 bfr = *(const bf16x8*)&Bs[(nt * 16 + fr) * 64 + go];
        acc[nt] = __builtin_amdgcn_mfma_f32_16x16x32_bf16(af, bfr, acc[nt], 0, 0, 0);
      }
    }
  }
  float* Cs = P + (size_t)s * MP * 32;
  const int rbase = row0 + wave * 16 + (lane >> 4) * 4;
  const int cbase = lane & 15;
#pragma unroll
  for (int nt = 0; nt < 2; ++nt) {
    const int cc = cbase + nt * 16;
#pragma unroll
    for (int r = 0; r < 4; ++r)
      Cs[(size_t)(rbase + r) * 32 + cc] = acc[nt][r];
  }
}

// ---------------------------------------------------------------------------
// bf16 MFMA GEMM, 2-phase double-buffered (T3-minimum):
// stage(t+1) issued BEFORE compute(t); single barrier per K-step whose
// implicit vmcnt(0) drains the PREVIOUS stage — loads overlap compute.
// Tile 64 x NT, BK=64, split-K into padded partial buffer (no mask).
// ---------------------------------------------------------------------------
template <int NT>
__global__ __launch_bounds__(256)
void gemm_bf16(const short* __restrict__ A, int lda,
               const short* __restrict__ Bt, int ldb,
               float* __restrict__ C, long long cSplitStride, int ldc,
               int kChunks, int S) {
  __shared__ short As[2][64 * 64];
  __shared__ short Bs[2][NT * 64];
  const int tid  = threadIdx.x;
  const int wave = tid >> 6;
  const int lane = tid & 63;
  const int row0 = blockIdx.y * 64;
  const int col0 = blockIdx.x * NT;
  const int s    = blockIdx.z;
  const int t0 = (int)((long long)s * kChunks / S);
  const int t1 = (int)((long long)(s + 1) * kChunks / S);

  f32x4 acc[NT / 16];
#pragma unroll
  for (int i = 0; i < NT / 16; ++i) acc[i] = (f32x4){0.f, 0.f, 0.f, 0.f};

  const int lr = lane >> 3;
  const int lk = ((lane & 7) ^ lr) * 8;
  const int fr = lane & 15, fq = lane >> 4, sw = lane & 7;

  auto stage = [&](int b, int t) {
    const int k0 = t * 64;
#pragma unroll
    for (int i = 0; i < 2; ++i) {
      int c = wave + 4 * i;
      gl_lds16(A + (size_t)(row0 + 8 * c + lr) * lda + k0 + lk,
               (void*)(&As[b][c * 512]));
    }
#pragma unroll
    for (int i = 0; i < NT / 32; ++i) {
      int c = wave + 4 * i;
      gl_lds16(Bt + (size_t)(col0 + 8 * c + lr) * ldb + k0 + lk,
               (void*)(&Bs[b][c * 512]));
    }
  };

  stage(0, t0);
  for (int t = t0; t < t1; ++t) {
    const int b = (t - t0) & 1;
    __syncthreads();                    // drains stage(b,t); frees buf b^1
    if (t + 1 < t1) stage(b ^ 1, t + 1);
#pragma unroll
    for (int ks = 0; ks < 2; ++ks) {
      const int go = ((ks * 4 + fq) ^ sw) * 8;
      bf16x8 af = *(const bf16x8*)&As[b][(wave * 16 + fr) * 64 + go];
#pragma unroll
      for (int nt = 0; nt < NT / 16; ++nt) {
        bf16x8 bfr = *(const bf16x8*)&Bs[b][(nt * 16 + fr) * 64 + go];
        acc[nt] = __builtin_amdgcn_mfma_f32_16x16x32_bf16(af, bfr, acc[nt], 0, 0, 0);
      }
    }
  }

  float* Cs = C + (long long)s * cSplitStride;
  const int rbase = row0 + wave * 16 + (lane >> 4) * 4;
  const int cbase = col0 + (lane & 15);
#pragma unroll
  for (int nt = 0; nt < NT / 16; ++nt) {
    const int cc = cbase + nt * 16;
#pragma unroll
    for (int r = 0; r < 4; ++r)
      Cs[(size_t)(rbase + r) * ldc + cc] = acc[nt][r];
  }
}

// ---------------------------------------------------------------------------
// Recon GEMM: out1 = sigmoid(hb @ g3b^T), 128x128 tile, K=128 (2 chunks).
// hb [MP2][128] bf16 (rows >= NROWS zeroed), g3b [MP2][128] bf16.
// ---------------------------------------------------------------------------
__global__ __launch_bounds__(256)
void gemm_recon(const short* __restrict__ A, const short* __restrict__ Bt,
                float* __restrict__ C) {
  __shared__ short As[128 * 64];
  __shared__ short Bs[128 * 64];
  const int tid  = threadIdx.x;
  const int wave = tid >> 6;
  const int lane = tid & 63;
  const int row0 = blockIdx.y * 128;
  const int col0 = blockIdx.x * 128;

  f32x4 acc[2][8];
#pragma unroll
  for (int i = 0; i < 2; ++i)
#pragma unroll
    for (int j = 0; j < 8; ++j) acc[i][j] = (f32x4){0.f, 0.f, 0.f, 0.f};

  const int lr = lane >> 3;
  const int lk = ((lane & 7) ^ lr) * 8;
  const int fr = lane & 15, fq = lane >> 4, sw = lane & 7;

  for (int t = 0; t < 2; ++t) {
    const int k0 = t * 64;
    __syncthreads();
#pragma unroll
    for (int i = 0; i < 4; ++i) {
      int c = wave + 4 * i;
      gl_lds16(A + (size_t)(row0 + 8 * c + lr) * 128 + k0 + lk, (void*)(As + c * 512));
      gl_lds16(Bt + (size_t)(col0 + 8 * c + lr) * 128 + k0 + lk, (void*)(Bs + c * 512));
    }
    __syncthreads();
#pragma unroll
    for (int ks = 0; ks < 2; ++ks) {
      const int go = ((ks * 4 + fq) ^ sw) * 8;
      bf16x8 a0 = *(const bf16x8*)&As[(wave * 32 + fr) * 64 + go];
      bf16x8 a1 = *(const bf16x8*)&As[(wave * 32 + 16 + fr) * 64 + go];
#pragma unroll
      for (int nt = 0; nt < 8; ++nt) {
        bf16x8 bfr = *(const bf16x8*)&Bs[(nt * 16 + fr) * 64 + go];
        acc[0][nt] = __builtin_amdgcn_mfma_f32_16x16x32_bf16(a0, bfr, acc[0][nt], 0, 0, 0);
        acc[1][nt] = __builtin_amdgcn_mfma_f32_16x16x32_bf16(a1, bfr, acc[1][nt], 0, 0, 0);
      }
    }
  }

  const int q = lane >> 4;
#pragma unroll
  for (int mf = 0; mf < 2; ++mf) {
    const int rb = row0 + wave * 32 + mf * 16 + q * 4;
#pragma unroll
    for (int nt = 0; nt < 8; ++nt) {
      const int cc = col0 + nt * 16 + (lane & 15);
      if (cc >= NROWS) continue;
#pragma unroll
      for (int r = 0; r < 4; ++r) {
        const int rr = rb + r;
        if (rr < NROWS) {
          float v = acc[mf][nt][r];
          v = 1.0f / (1.0f + __expf(-v));
          C[(size_t)rr * NROWS + cc] = v;
        }
      }
    }
  }
}

// ---------------------------------------------------------------------------
// f32 tiled GEMMs for the small (K<=256) ops. 64x64 tile, 4x4/thread.
// ---------------------------------------------------------------------------
#define TK 16
#define TM 64
#define TN 64

template <int ACT, bool OBF16>
__global__ __launch_bounds__(256)
void gemm_nn_f32(const float* __restrict__ A, int lda,
                 const float* __restrict__ B, int ldb,
                 void* __restrict__ Cp, int ldc, int M, int N, int K) {
  __shared__ float Asm[TK][TM + 4];
  __shared__ float Bsm[TK][TN + 4];
  const int tid = threadIdx.x;
  const int tx = tid & 15, ty = tid >> 4;
  const int row0 = blockIdx.y * TM, col0 = blockIdx.x * TN;
  const int a_m = tid >> 2, a_k = (tid & 3) << 2;
  const int b_k = tid >> 4, b_n = (tid & 15) << 2;
  float acc[4][4] = {};
  const int ntile = (K + TK - 1) / TK;

  auto ld_a = [&](int k0) {
    float4 v = make_float4(0.f, 0.f, 0.f, 0.f);
    int r = row0 + a_m, k = k0 + a_k;
    if (r < M && k < K) v = *(const float4*)(A + (size_t)r * lda + k);
    return v;
  };
  auto ld_b = [&](int k0) {
    float4 v = make_float4(0.f, 0.f, 0.f, 0.f);
    int k = k0 + b_k, c = col0 + b_n;
    if (k < K && c + 3 < N) v = *(const float4*)(B + (size_t)k * ldb + c);
    return v;
  };

  float4 pa = ld_a(0), pb = ld_b(0);
  for (int t = 0; t < ntile; ++t) {
    __syncthreads();
    Asm[a_k + 0][a_m] = pa.x; Asm[a_k + 1][a_m] = pa.y;
    Asm[a_k + 2][a_m] = pa.z; Asm[a_k + 3][a_m] = pa.w;
    *(float4*)&Bsm[b_k][b_n] = pb;
    __syncthreads();
    if (t + 1 < ntile) { pa = ld_a((t + 1) * TK); pb = ld_b((t + 1) * TK); }
#pragma unroll
    for (int kk = 0; kk < TK; ++kk) {
      float4 a = *(const float4*)&Asm[kk][ty << 2];
      float4 b = *(const float4*)&Bsm[kk][tx << 2];
      float av[4] = {a.x, a.y, a.z, a.w};
      float bv[4] = {b.x, b.y, b.z, b.w};
#pragma unroll
      for (int i = 0; i < 4; ++i)
#pragma unroll
        for (int j = 0; j < 4; ++j) acc[i][j] += av[i] * bv[j];
    }
  }
#pragma unroll
  for (int i = 0; i < 4; ++i) {
    int r = row0 + (ty << 2) + i;
    if (r >= M) continue;
#pragma unroll
    for (int j = 0; j < 4; ++j) {
      int c = col0 + (tx << 2) + j;
      if (c >= N) continue;
      float v = acc[i][j];
      if (ACT == 1) v = tanhf(v);
      if (OBF16) ((unsigned short*)Cp)[(size_t)r * ldc + c] = f2bf(v);
      else       ((float*)Cp)[(size_t)r * ldc + c] = v;
    }
  }
}

template <int ACT>
__global__ __launch_bounds__(256)
void gemm_nt_f32(const float* __restrict__ A, int lda,
                 const float* __restrict__ B, int ldb,
                 float* __restrict__ C, int ldc, int M, int N, int K) {
  __shared__ float Asm[TK][TM + 4];
  __shared__ float Bsm[TK][TN + 4];
  const int tid = threadIdx.x;
  const int tx = tid & 15, ty = tid >> 4;
  const int row0 = blockIdx.y * TM, col0 = blockIdx.x * TN;
  const int a_m = tid >> 2, a_k = (tid & 3) << 2;
  const int b_n = tid >> 2, b_k = (tid & 3) << 2;
  float acc[4][4] = {};
  const int ntile = (K + TK - 1) / TK;

  auto ld_a = [&](int k0) {
    float4 v = make_float4(0.f, 0.f, 0.f, 0.f);
    int r = row0 + a_m, k = k0 + a_k;
    if (r < M && k + 3 < K) v = *(const float4*)(A + (size_t)r * lda + k);
    return v;
  };
  auto ld_b = [&](int k0) {
    float4 v = make_float4(0.f, 0.f, 0.f, 0.f);
    int c = col0 + b_n, k = k0 + b_k;
    if (c < N && k + 3 < K) v = *(const float4*)(B + (size_t)c * ldb + k);
    return v;
  };

  float4 pa = ld_a(0), pb = ld_b(0);
  for (int t = 0; t < ntile; ++t) {
    __syncthreads();
    Asm[a_k + 0][a_m] = pa.x; Asm[a_k + 1][a_m] = pa.y;
    Asm[a_k + 2][a_m] = pa.z; Asm[a_k + 3][a_m] = pa.w;
    Bsm[b_k + 0][b_n] = pb.x; Bsm[b_k + 1][b_n] = pb.y;
    Bsm[b_k + 2][b_n] = pb.z; Bsm[b_k + 3][b_n] = pb.w;
    __syncthreads();
    if (t + 1 < ntile) { pa = ld_a((t + 1) * TK); pb = ld_b((t + 1) * TK); }
#pragma unroll
    for (int kk = 0; kk < TK; ++kk) {
      float4 a = *(const float4*)&Asm[kk][ty << 2];
      float4 b = *(const float4*)&Bsm[kk][tx << 2];
      float av[4] = {a.x, a.y, a.z, a.w};
      float bv[4] = {b.x, b.y, b.z, b.w};
#pragma unroll
      for (int i = 0; i < 4; ++i)
#pragma unroll
        for (int j = 0; j < 4; ++j) acc[i][j] += av[i] * bv[j];
    }
  }
#pragma unroll
  for (int i = 0; i < 4; ++i) {
    int r = row0 + (ty << 2) + i;
    if (r >= M) continue;
#pragma unroll
    for (int j = 0; j < 4; ++j) {
      int c = col0 + (tx << 2) + j;
      if (c >= N) continue;
      C[(size_t)r * ldc + c] = acc[i][j];
    }
  }
}

// --------------------------- helper kernels --------------------------------

__global__ void tr_zigae(const float* __restrict__ z, short* __restrict__ zt) {
  int m = blockIdx.x * 256 + threadIdx.x;  // up to 10240
  int n = blockIdx.y;                      // 32
  if (m >= MP) return;
  float v = (n < 20 && m < NROWS) ? z[(size_t)m * 20 + n] : 0.f;
  zt[(size_t)n * MP + m] = f2bf(v);
}

// [M][128] f32 -> [128][MP] bf16 (zero pad m>=M)
__global__ void transpose_c128(const float* __restrict__ in, int M,
                               short* __restrict__ out) {
  __shared__ float tile[32][33];
  int m0 = blockIdx.x * 32, n0 = blockIdx.y * 32;
  int tx = threadIdx.x, ty = threadIdx.y;  // 32 x 8
  for (int i = ty; i < 32; i += 8) {
    int m = m0 + i;
    tile[i][tx] = (m < M) ? in[(size_t)m * 128 + n0 + tx] : 0.f;
  }
  __syncthreads();
  for (int i = ty; i < 32; i += 8) {
    int n = n0 + i, m = m0 + tx;
    if (m < MP) out[(size_t)n * MP + m] = f2bf(tile[tx][i]);
  }
}

__global__ void reduce_g1(const float* __restrict__ P, float* __restrict__ g1) {
  int m = blockIdx.x * 4 + (threadIdx.x >> 5);
  int n = threadIdx.x & 31;
  if (m >= NROWS) return;
  float s = 0.f;
#pragma unroll
  for (int i = 0; i < 8; ++i) s += P[(size_t)i * MP * 32 + (size_t)m * 32 + n];
  g1[(size_t)m * 32 + n] = s;
}

// Fused: sum 8 partials -> tanh -> transposed bf16 [128][MP] (zero m>=NROWS)
__global__ __launch_bounds__(256)
void reduce_tr(const float* __restrict__ P, short* __restrict__ z2t) {
  __shared__ float T[128][33];
  const int tid = threadIdx.x;
  const int m0 = blockIdx.x * 32;
  const int mr = tid >> 5;            // 0..7
  const int n0 = (tid & 31) * 4;      // 0..124
#pragma unroll
  for (int g = 0; g < 4; ++g) {
    const int mm = g * 8 + mr;
    const int m = m0 + mm;
    f32x4 sAcc = (f32x4){0.f, 0.f, 0.f, 0.f};
#pragma unroll
    for (int i = 0; i < 8; ++i) {
      f32x4 v = *(const f32x4*)(P + (size_t)i * MP * 128 + (size_t)m * 128 + n0);
      sAcc += v;
    }
    if (m < NROWS) {
      T[n0 + 0][mm] = tanhf(sAcc[0]); T[n0 + 1][mm] = tanhf(sAcc[1]);
      T[n0 + 2][mm] = tanhf(sAcc[2]); T[n0 + 3][mm] = tanhf(sAcc[3]);
    } else {
      T[n0 + 0][mm] = 0.f; T[n0 + 1][mm] = 0.f;
      T[n0 + 2][mm] = 0.f; T[n0 + 3][mm] = 0.f;
    }
  }
  __syncthreads();
  const int n = tid >> 1, mh = (tid & 1) * 16;
  unsigned short h[16] __attribute__((aligned(16)));
#pragma unroll
  for (int j = 0; j < 16; ++j) h[j] = f2bf(T[n][mh + j]);
  *(uint4*)(z2t + (size_t)n * MP + m0 + mh)     = *(const uint4*)&h[0];
  *(uint4*)(z2t + (size_t)n * MP + m0 + mh + 8) = *(const uint4*)&h[8];
}

template <int ACT>  // 1 = tanh
__global__ void reduce128(const float* __restrict__ P, float* __restrict__ outf,
                          short* __restrict__ outb, int M) {
  int m = blockIdx.x, n = threadIdx.x;
  if (m >= M) { if (outb) outb[(size_t)m * 128 + n] = 0; return; }
  float s = 0.f;
#pragma unroll
  for (int i = 0; i < 8; ++i) s += P[(size_t)i * MP * 128 + (size_t)m * 128 + n];
  if (ACT == 1) s = tanhf(s);
  if (outf) outf[(size_t)m * 128 + n] = s;
  if (outb) outb[(size_t)m * 128 + n] = f2bf(s);
}

__global__ void zero_bf16(short* p, int n) {
  int i = blockIdx.x * 256 + threadIdx.x;
  if (i < n) p[i] = 0;
}

// ---------------------------------------------------------------------------
extern "C" void kernel_launch(void* const* d_in, const int* in_sizes, int n_in,
                              void* d_out, int out_size, void* d_ws, size_t ws_size,
                              hipStream_t stream) {
  const float* z_igae = (const float*)d_in[0];
  const float* adj    = (const float*)d_in[1];
  const float* w3     = (const float*)d_in[2];
  const float* w4     = (const float*)d_in[3];
  const float* w5     = (const float*)d_in[4];

  const int M = NROWS, D2 = 256, D3 = 128, NI = 500;
  const int S = 8, KC = MP / 64;  // 157 BK-chunks

  float* z_hat   = (float*)d_out;                         // [M, NI]
  float* out_adj = (float*)d_out + (size_t)M * NI;        // [M, M] = 400 MB

  // scratch inside out_adj region (overwritten only by the final recon GEMM)
  char* oa = (char*)out_adj;
  short* adjb = (short*)oa;                               // [MP][MP] bf16, 192.6 MiB
  float* P    = (float*)(oa + 204ll * 1024 * 1024);       // partials 8*MP*128*4 = 39.3 MiB
  char*  sc   = oa + 248ll * 1024 * 1024;                 // scratch, ends < 290 MiB
  float* z1   = (float*)(sc);                             // [M][256] 10.3 MB
  float* t2   = (float*)(sc + 11ll * 1024 * 1024);        // [M][128]  5.2 MB
  short* t2t  = (short*)(sc + 17ll * 1024 * 1024);        // [128][MP] 2.6 MB
  short* z2t  = (short*)(sc + 20ll * 1024 * 1024);        // [128][MP] 2.6 MB
  float* g1   = (float*)(sc + 23ll * 1024 * 1024);        // [M][32]   1.3 MB
  short* zt   = (short*)(sc + 25ll * 1024 * 1024);        // [32][MP]  0.65 MB
  float* Mm   = (float*)(sc + 26ll * 1024 * 1024);        // [128][128] 64 KB
  float* g3   = (float*)(sc + 27ll * 1024 * 1024);        // [M][128]  5.2 MB

  // recon inputs live in d_ws (must survive until recon writes out_adj)
  short* hb  = (short*)d_ws;                              // [MP2][128]  2.59 MB
  short* g3b = (short*)d_ws + (size_t)MP2 * 128;          // [MP2][128]  2.59 MB

  dim3 blk(256);
  const int MT = 157;

  // 1. z_igae^T -> bf16 [32][MP]
  tr_zigae<<<dim3(40, 32), blk, 0, stream>>>(z_igae, zt);
  // 2. fused: adj f32 -> adjb bf16 AND g1 partials (split-K)
  gemm1_fused<<<dim3(1, MT, S), blk, 0, stream>>>(adj, zt, adjb, P, KC, S);
  reduce_g1<<<dim3(2500), dim3(128), 0, stream>>>(P, g1);
  // 3. z1 = tanh(g1 @ w3)
  gemm_nn_f32<1, false><<<dim3(4, MT), blk, 0, stream>>>(g1, 32, w3, D2, z1, D2, M, D2, 20);
  // 4. t2 = z1 @ w4
  gemm_nn_f32<0, false><<<dim3(2, MT), blk, 0, stream>>>(z1, D2, w4, D3, t2, D3, M, D3, D2);
  transpose_c128<<<dim3(314, 4), dim3(32, 8), 0, stream>>>(t2, M, t2t);
  // 5. z2 partials = adj @ t2 (2-phase dbuf), then fused reduce+tanh+transpose
  gemm_bf16<128><<<dim3(1, MT, S), blk, 0, stream>>>(
      adjb, MP, t2t, MP, P, (long long)MP * 128, 128, KC, S);
  reduce_tr<<<dim3(314), blk, 0, stream>>>(P, z2t);
  // 6. g3 = adj @ z2
  gemm_bf16<128><<<dim3(1, MT, S), blk, 0, stream>>>(
      adjb, MP, z2t, MP, P, (long long)MP * 128, 128, KC, S);
  reduce128<0><<<dim3(MP2), dim3(128), 0, stream>>>(P, g3, g3b, M);
  // 7. z_hat = g3 @ w5 -> out0
  gemm_nn_f32<0, false><<<dim3(8, MT), blk, 0, stream>>>(g3, D3, w5, NI, z_hat, NI, M, NI, D3);
  // 8. Mm = w5 @ w5^T
  gemm_nt_f32<0><<<dim3(2, 2), blk, 0, stream>>>(w5, NI, w5, NI, Mm, D3, D3, D3, NI);
  // 9. h = g3 @ Mm (bf16 out) + zero pad rows 10000..10111
  gemm_nn_f32<0, true><<<dim3(2, MT), blk, 0, stream>>>(g3, D3, Mm, D3, (void*)hb, D3, M, D3, D3);
  zero_bf16<<<dim3(56), blk, 0, stream>>>(hb + (size_t)M * 128, (MP2 - M) * 128);
  // 10. out1 = sigmoid(h @ g3^T) — overwrites all scratch in out_adj
  gemm_recon<<<dim3(79, 79), blk, 0, stream>>>(hb, g3b, out_adj);
}